// Round 11
// baseline (403.903 us; speedup 1.0000x reference)
//
#include <hip/hip_runtime.h>

// Bahdanau attention fused kernel for MI355X (gfx950).
// scores[b][s] = softmax_s( v . tanh( hb[b,:] + enc[s,b,:] @ We ) )
// R11: A direct global->reg->cvt per lane (no A LDS, no ds_write). B in an
//      8-slot LDS ring staged 4 steps ahead via gload_lds; one drain-free
//      s_barrier + one counted vmcnt(10) per BK=32 step. 32 MFMA/step/wave.

typedef _Float16 f16;
typedef _Float16 half8 __attribute__((ext_vector_type(8)));
typedef float f32x4 __attribute__((ext_vector_type(4)));

#define KDIM 1024
#define SEQ  2048
#define MROWS 65536

typedef __attribute__((address_space(1))) void gvoid;
typedef __attribute__((address_space(3))) void svoid;

__device__ __forceinline__ void gload_lds16(const void* g, void* l) {
    __builtin_amdgcn_global_load_lds((const gvoid*)g, (svoid*)l, 16, 0, 0);
}

// ---------------------------------------------------------------------------
// prep_w: transpose + f16-convert enc-half of attn_w into subtile images.
// Subtile tk = nq*32 + ks (ks = k/32): [256 n][32 k] LDS image, 16B block
// p = nloc*4 + ((kblk + (nloc>>1)) & 3); payload k = 1024 + ks*32 + kblk*8 + j.
// ---------------------------------------------------------------------------
__global__ __launch_bounds__(256) void prep_w(const float* __restrict__ w,
                                              f16* __restrict__ wt) {
    int idx  = blockIdx.x * 256 + threadIdx.x;   // 0..131071
    int kblk = idx & 3;
    int nloc = (idx >> 2) & 255;
    int tk   = idx >> 10;                        // 0..127
    int ks   = tk & 31, nq = tk >> 5;
    int n_g  = nq * 256 + nloc;
    int kb   = 1024 + ks * 32 + kblk * 8;
    half8 h;
#pragma unroll
    for (int j = 0; j < 8; ++j)
        h[j] = (f16)w[(size_t)(kb + j) * 1024 + n_g];
    int p = nloc * 4 + ((kblk + (nloc >> 1)) & 3);
    *(half8*)&wt[(size_t)tk * 8192 + p * 8] = h;
}

// ---------------------------------------------------------------------------
// prep_hb: hb[b][n] = attn_b[n] + sum_k hidden[b][k] * attn_w[k][n]  (f32)
// ---------------------------------------------------------------------------
__global__ __launch_bounds__(256) void prep_hb(const float* __restrict__ hidden,
                                               const float* __restrict__ attn_w,
                                               const float* __restrict__ attn_b,
                                               float* __restrict__ hb) {
    int b = blockIdx.x >> 2;
    int n = (blockIdx.x & 3) * 256 + threadIdx.x;
    const float* h = hidden + (size_t)b * 1024;
    float acc = attn_b[n];
#pragma unroll 8
    for (int k = 0; k < 1024; ++k)
        acc += h[k] * attn_w[(size_t)k * 1024 + n];
    hb[(size_t)b * 1024 + n] = acc;
}

// ---------------------------------------------------------------------------
// fused_energy: block = 256 rows x 256 N-slice, K=1024 in 32 steps of BK=32.
// 8 waves: wm = wv>>1 (64-row group), wn = wv&1 (128-col half). Per wave-step:
// 8 A global loads (direct-to-frag), 2 B gload_lds (4 steps ahead), vmcnt(10),
// 16 cvt, 8 ds_read_b128, 32 MFMA. One drain-free barrier per step.
// ---------------------------------------------------------------------------
__global__ __launch_bounds__(512, 2)
void fused_energy(const float* __restrict__ enc, const f16* __restrict__ wt,
                  const float* __restrict__ hb, const float* __restrict__ vvec,
                  float* __restrict__ partout) {
    __shared__ f16 Bls[8][8192];      // 8 slots x 16 KB B ring
    __shared__ float red[2][256];

    const int tid  = threadIdx.x;
    const int lane = tid & 63;
    const int wv   = tid >> 6;          // 0..7
    const int wm   = wv >> 1;           // 0..3: 64-row group
    const int wn   = wv & 1;            // 0..1: 128-col half
    const int l15  = lane & 15;
    const int l4   = lane >> 4;

    // XCD-bijective mapping: same-row nq-quads co-XCD for L2/L3 A dedupe
    const int bid   = blockIdx.x;       // 0..1023
    const int xcd   = bid & 7;
    const int chunk = bid >> 3;         // 0..127
    const int mt    = xcd * 32 + (chunk >> 2);   // 0..255
    const int nq    = chunk & 3;
    const int mrow0 = mt * 256;
    const int ncol0 = nq * 256;

    const char* wtNq = (const char*)wt + (size_t)nq * 32 * 16384;

    // A fragment base pointers: lane reads enc[row = mrow0+wm*64+mi*16+l15][k = j*32 + l4*8 ..+7]
    const float* aB0 = enc + (size_t)(mrow0 + wm * 64 +  0 + l15) * KDIM + l4 * 8;
    const float* aB1 = enc + (size_t)(mrow0 + wm * 64 + 16 + l15) * KDIM + l4 * 8;
    const float* aB2 = enc + (size_t)(mrow0 + wm * 64 + 32 + l15) * KDIM + l4 * 8;
    const float* aB3 = enc + (size_t)(mrow0 + wm * 64 + 48 + l15) * KDIM + l4 * 8;

    int bOffB[8];
#pragma unroll
    for (int nj = 0; nj < 8; ++nj) {
        int n = wn * 128 + nj * 16 + l15;
        bOffB[nj] = (n * 4 + ((l4 + (n >> 1)) & 3)) * 16;
    }

    const f32x4 zero = {0.f, 0.f, 0.f, 0.f};
    f32x4 acc[4][8];
#pragma unroll
    for (int mi = 0; mi < 4; ++mi)
#pragma unroll
        for (int nj = 0; nj < 8; ++nj) acc[mi][nj] = zero;

    f32x4 rAa[8], rAb[8];     // two A prefetch sets (parity by step)
    half8 af[4];

#define WAITV(N) asm volatile("s_waitcnt vmcnt(" #N ")" ::: "memory")
#define BAR      __builtin_amdgcn_s_barrier()
#define PRIO1    __builtin_amdgcn_s_setprio(1)
#define PRIO0    __builtin_amdgcn_s_setprio(0)

#define STAGE_B(J)                                                            \
    {                                                                         \
        const char* s_ = wtNq + (size_t)(J) * 16384 + tid * 16;               \
        char* d_ = (char*)&Bls[(J) & 7][0] + tid * 16;                        \
        gload_lds16(s_, d_);                                                  \
        gload_lds16(s_ + 8192, d_ + 8192);                                    \
    }
#define LOADA(J, R)                                                           \
    {                                                                         \
        R[0] = *(const f32x4*)(aB0 + (J) * 32); R[1] = *(const f32x4*)(aB0 + (J) * 32 + 4); \
        R[2] = *(const f32x4*)(aB1 + (J) * 32); R[3] = *(const f32x4*)(aB1 + (J) * 32 + 4); \
        R[4] = *(const f32x4*)(aB2 + (J) * 32); R[5] = *(const f32x4*)(aB2 + (J) * 32 + 4); \
        R[6] = *(const f32x4*)(aB3 + (J) * 32); R[7] = *(const f32x4*)(aB3 + (J) * 32 + 4); \
    }
#define CVTA(R)                                                               \
    _Pragma("unroll") for (int mi = 0; mi < 4; ++mi)                          \
        _Pragma("unroll") for (int j = 0; j < 4; ++j) {                       \
            af[mi][j]     = (f16)R[2 * mi][j];                                \
            af[mi][4 + j] = (f16)R[2 * mi + 1][j];                            \
        }
#define COMPUTE(J)                                                            \
    {                                                                         \
        const char* bb_ = (const char*)&Bls[(J) & 7][0];                      \
        PRIO1;                                                                \
        _Pragma("unroll") for (int nj = 0; nj < 8; ++nj) {                    \
            half8 bf_ = *(const half8*)(bb_ + bOffB[nj]);                     \
            _Pragma("unroll") for (int mi = 0; mi < 4; ++mi)                  \
                acc[mi][nj] = __builtin_amdgcn_mfma_f32_16x16x32_f16(         \
                    af[mi], bf_, acc[mi][nj], 0, 0, 0);                       \
        }                                                                     \
        PRIO0;                                                                \
    }
// Steady step: barrier (no drain) | A(j+1) issue | B(j+4) stage | vmcnt(10)
// retires exactly {A(j)x8, B(j+3)x2} (each >=1 full step old) | cvt | compute.
#define STEP(J, CONS, LOAD)                                                   \
    {                                                                         \
        BAR;                                                                  \
        LOADA((J) + 1, LOAD);                                                 \
        STAGE_B((J) + 4);                                                     \
        WAITV(10);                                                            \
        CVTA(CONS);                                                           \
        COMPUTE(J);                                                           \
    }

    // ---- prologue: B(0..3) staged, A(0) loaded+retired; no drain afterwards ----
    STAGE_B(0); STAGE_B(1); STAGE_B(2); STAGE_B(3);
    LOADA(0, rAa);
    WAITV(0);

    // ---- main loop: j = 0..27 (A parity: even->rAa, odd->rAb) ----
    for (int j = 0; j < 28; j += 2) {
        STEP(j,     rAa, rAb);
        STEP(j + 1, rAb, rAa);
    }
    // ---- peeled tail: j = 28..31 (no more B stages; A winds down) ----
    BAR; LOADA(29, rAb); WAITV(8); CVTA(rAa); COMPUTE(28);
    BAR; LOADA(30, rAa); WAITV(8); CVTA(rAb); COMPUTE(29);
    BAR; LOADA(31, rAb); WAITV(8); CVTA(rAa); COMPUTE(30);
    BAR;                 WAITV(0); CVTA(rAb); COMPUTE(31);

#undef STAGE_B
#undef LOADA
#undef CVTA
#undef COMPUTE
#undef STEP

    // ---- epilogue: e = acc + hb -> tanh -> * v -> per-row partial ----
    float vv[8];
#pragma unroll
    for (int nj = 0; nj < 8; ++nj)
        vv[nj] = vvec[ncol0 + wn * 128 + nj * 16 + l15];
#pragma unroll
    for (int mi = 0; mi < 4; ++mi) {
#pragma unroll
        for (int rg = 0; rg < 4; ++rg) {
            int rl = wm * 64 + mi * 16 + l4 * 4 + rg;     // local row 0..255
            const float* hbrow = hb + (size_t)((mrow0 + rl) & 31) * 1024
                                 + ncol0 + wn * 128 + l15;
            float sum = 0.f;
#pragma unroll
            for (int nj = 0; nj < 8; ++nj) {
                float e  = acc[mi][nj][rg] + hbrow[nj * 16];
                float e2 = __expf(2.f * e);
                sum += (1.f - 2.f / (e2 + 1.f)) * vv[nj];  // tanh(e) * v
            }
            float p = sum;
            p += __shfl_xor(p, 1);
            p += __shfl_xor(p, 2);
            p += __shfl_xor(p, 4);
            p += __shfl_xor(p, 8);
            if (l15 == 0) red[wn][rl] = p;
        }
    }
    __syncthreads();
    if (tid < 256) {
        float s = red[0][tid] + red[1][tid];
        partout[(size_t)nq * MROWS + mrow0 + tid] = s;
    }
}

// ---------------------------------------------------------------------------
// softmax over S=2048 per batch row; sums the 4 N-slice partials first.
// ---------------------------------------------------------------------------
__global__ __launch_bounds__(256) void softmax_rows(const float* __restrict__ part,
                                                    float* __restrict__ out) {
    const int b = blockIdx.x;
    const int tid  = threadIdx.x;
    const int lane = tid & 63;
    const int wv   = tid >> 6;
    __shared__ float sred[4];
    __shared__ float ssum[4];
    float x[8];
    float mx = -3.4e38f;
#pragma unroll
    for (int j = 0; j < 8; ++j) {
        int flat = (tid + j * 256) * 32 + b;              // row = s*32 + b
        float v = part[flat] + part[MROWS + flat]
                + part[2 * MROWS + flat] + part[3 * MROWS + flat];
        x[j] = v;
        mx = fmaxf(mx, v);
    }
#pragma unroll
    for (int o = 1; o < 64; o <<= 1) mx = fmaxf(mx, __shfl_xor(mx, o));
    if (lane == 0) sred[wv] = mx;
    __syncthreads();
    mx = fmaxf(fmaxf(sred[0], sred[1]), fmaxf(sred[2], sred[3]));
    float s = 0.f;
#pragma unroll
    for (int j = 0; j < 8; ++j) { x[j] = __expf(x[j] - mx); s += x[j]; }
#pragma unroll
    for (int o = 1; o < 64; o <<= 1) s += __shfl_xor(s, o);
    if (lane == 0) ssum[wv] = s;
    __syncthreads();
    s = ssum[0] + ssum[1] + ssum[2] + ssum[3];
    float inv = 1.f / s;
#pragma unroll
    for (int j = 0; j < 8; ++j) out[(size_t)b * SEQ + tid + j * 256] = x[j] * inv;
}

extern "C" void kernel_launch(void* const* d_in, const int* in_sizes, int n_in,
                              void* d_out, int out_size, void* d_ws, size_t ws_size,
                              hipStream_t stream) {
    const float* hidden = (const float*)d_in[0];   // [32][1024]
    const float* enc    = (const float*)d_in[1];   // [2048][32][1024]
    const float* attn_w = (const float*)d_in[2];   // [2048][1024]
    const float* attn_b = (const float*)d_in[3];   // [1024]
    const float* v      = (const float*)d_in[4];   // [1024]
    float* out = (float*)d_out;                    // [32][2048]

    f16*   wt   = (f16*)d_ws;                            // 2 MB tiled We
    float* hb   = (float*)((char*)d_ws + 2097152);       // 128 KB
    float* part = (float*)((char*)d_ws + 2097152 + 131072); // 1 MB N-partials

    prep_w<<<512, 256, 0, stream>>>(attn_w, wt);
    prep_hb<<<128, 256, 0, stream>>>(hidden, attn_w, attn_b, hb);
    fused_energy<<<1024, 512, 0, stream>>>(enc, wt, hb, v, part);
    softmax_rows<<<32, 256, 0, stream>>>(part, out);
}

// Round 14
// 295.492 us; speedup vs baseline: 1.3669x; 1.3669x over previous
//
#include <hip/hip_runtime.h>

// Bahdanau attention fused kernel for MI355X (gfx950).
// scores[b][s] = softmax_s( v . tanh( hb[b,:] + enc[s,b,:] @ We ) )
// R12: m97-replica occupancy regime. 128x128 tile, 256 thr / 4 waves,
//      LDS 25KB, launch_bounds(256,3) -> 3 independent blocks/CU.
//      No-drain loop: WAITV(2)/WAITV(6) counted waits (1-iter windows),
//      raw barriers with lgkm-only drains, B double-buffered, A reg->cvt->LDS.

typedef _Float16 f16;
typedef _Float16 half8 __attribute__((ext_vector_type(8)));
typedef float f32x4 __attribute__((ext_vector_type(4)));

#define KDIM 1024
#define SEQ  2048
#define MROWS 65536

typedef __attribute__((address_space(1))) void gvoid;
typedef __attribute__((address_space(3))) void svoid;

__device__ __forceinline__ void gload_lds16(const void* g, void* l) {
    __builtin_amdgcn_global_load_lds((const gvoid*)g, (svoid*)l, 16, 0, 0);
}

// ---------------------------------------------------------------------------
// prep_w: transpose + f16-convert enc-half of attn_w into [128 n][32 k] tile
// images. Tile tk = nq*32 + ks (nq 0..7, ks 0..31), 8KB each; 16B block
// p = nloc*4 + ((kblk + (nloc>>1)) & 3); payload k = 1024+ks*32+kblk*8+j.
// ---------------------------------------------------------------------------
__global__ __launch_bounds__(256) void prep_w(const float* __restrict__ w,
                                              f16* __restrict__ wt) {
    int idx  = blockIdx.x * 256 + threadIdx.x;   // 0..131071
    int kblk = idx & 3;
    int nloc = (idx >> 2) & 127;
    int tk   = idx >> 9;                         // 0..255
    int ks   = tk & 31, nq = tk >> 5;
    int n_g  = nq * 128 + nloc;
    int kb   = 1024 + ks * 32 + kblk * 8;
    half8 h;
#pragma unroll
    for (int j = 0; j < 8; ++j)
        h[j] = (f16)w[(size_t)(kb + j) * 1024 + n_g];
    int p = nloc * 4 + ((kblk + (nloc >> 1)) & 3);
    *(half8*)&wt[(size_t)tk * 4096 + p * 8] = h;
}

// ---------------------------------------------------------------------------
// prep_hb: hb[b][n] = attn_b[n] + sum_k hidden[b][k] * attn_w[k][n]  (f32)
// ---------------------------------------------------------------------------
__global__ __launch_bounds__(256) void prep_hb(const float* __restrict__ hidden,
                                               const float* __restrict__ attn_w,
                                               const float* __restrict__ attn_b,
                                               float* __restrict__ hb) {
    int b = blockIdx.x >> 2;
    int n = (blockIdx.x & 3) * 256 + threadIdx.x;
    const float* h = hidden + (size_t)b * 1024;
    float acc = attn_b[n];
#pragma unroll 8
    for (int k = 0; k < 1024; ++k)
        acc += h[k] * attn_w[(size_t)k * 1024 + n];
    hb[(size_t)b * 1024 + n] = acc;
}

// ---------------------------------------------------------------------------
// fused_energy: block = 128 rows x 128 N-slice (nq of 8); K = 32 steps of 32.
// 4 waves (2M x 2N), wave tile 64x64, frags 4(M) x 4(N), 16 MFMA/step/wave.
// Steady in-flight invariant across barriers: {A(ks)x4, B(ks)x2}.
// ---------------------------------------------------------------------------
__global__ __launch_bounds__(256, 3)
void fused_energy(const float* __restrict__ enc, const f16* __restrict__ wt,
                  const float* __restrict__ hb, const float* __restrict__ vvec,
                  float* __restrict__ partout) {
    __shared__ f16 Bls[2][4096];   // 2 x 8KB B double buffer
    __shared__ f16 Als[4096];      // 8KB A tile
    __shared__ float red[2][128];

    const int tid  = threadIdx.x;
    const int lane = tid & 63;
    const int wv   = tid >> 6;          // 0..3
    const int wm   = wv >> 1;           // 0..1: 64-row group
    const int wn   = wv & 1;            // 0..1: 64-col group
    const int l15  = lane & 15;
    const int l4   = lane >> 4;

    // XCD mapping: all 8 nq-slices of a row-tile consecutive on one XCD
    const int bid   = blockIdx.x;       // 0..4095
    const int xcd   = bid & 7;
    const int chunk = bid >> 3;         // 0..511
    const int mt    = xcd * 64 + (chunk >> 3);   // 0..511
    const int nq    = chunk & 7;                 // 0..7
    const int mrow0 = mt * 128;
    const int ncol0 = nq * 128;

    const char* wtNq = (const char*)wt + (size_t)nq * 32 * 8192;

    // A staging: thread -> (row arow, k-half akh): 16 f32 -> 16 f16 -> 2 writes
    const int arow = tid >> 1;          // 0..127
    const int akh  = tid & 1;
    const float* aG = enc + (size_t)(mrow0 + arow) * KDIM + akh * 16;
    const int pw0 = arow * 4 + ((akh * 2     + (arow >> 1)) & 3);
    const int pw1 = arow * 4 + ((akh * 2 + 1 + (arow >> 1)) & 3);

    int aOffB[4], bOffB[4];
#pragma unroll
    for (int mi = 0; mi < 4; ++mi) {
        int r = wm * 64 + mi * 16 + l15;
        aOffB[mi] = (r * 4 + ((l4 + (r >> 1)) & 3)) * 16;
    }
#pragma unroll
    for (int nj = 0; nj < 4; ++nj) {
        int n = wn * 64 + nj * 16 + l15;
        bOffB[nj] = (n * 4 + ((l4 + (n >> 1)) & 3)) * 16;
    }

    const f32x4 zero = {0.f, 0.f, 0.f, 0.f};
    f32x4 acc[4][4];
#pragma unroll
    for (int mi = 0; mi < 4; ++mi)
#pragma unroll
        for (int nj = 0; nj < 4; ++nj) acc[mi][nj] = zero;

    f32x4 rA[4];
    half8 bf[4], af[4];

#define WAITV(N) asm volatile("s_waitcnt vmcnt(" #N ")" ::: "memory")
#define LGKM0    asm volatile("s_waitcnt lgkmcnt(0)" ::: "memory")
#define BAR      __builtin_amdgcn_s_barrier()

#define STAGE_B(KS)                                                           \
    {                                                                         \
        const char* s_ = wtNq + (size_t)(KS) * 8192 + tid * 16;               \
        char* d_ = (char*)&Bls[(KS) & 1][0] + tid * 16;                       \
        gload_lds16(s_, d_);                                                  \
        gload_lds16(s_ + 4096, d_ + 4096);                                    \
    }
#define LOADA(KS)                                                             \
    {                                                                         \
        const float* p_ = aG + (KS) * 32;                                     \
        rA[0] = *(const f32x4*)(p_);      rA[1] = *(const f32x4*)(p_ + 4);    \
        rA[2] = *(const f32x4*)(p_ + 8);  rA[3] = *(const f32x4*)(p_ + 12);   \
    }
#define CVTA()                                                                \
    {                                                                         \
        half8 h0_, h1_;                                                       \
        _Pragma("unroll") for (int j = 0; j < 4; ++j) {                       \
            h0_[j] = (f16)rA[0][j]; h0_[4 + j] = (f16)rA[1][j];               \
            h1_[j] = (f16)rA[2][j]; h1_[4 + j] = (f16)rA[3][j];               \
        }                                                                     \
        *(half8*)((char*)Als + pw0 * 16) = h0_;                               \
        *(half8*)((char*)Als + pw1 * 16) = h1_;                               \
    }
#define COMPUTE(KS)                                                           \
    {                                                                         \
        const char* bb_ = (const char*)&Bls[(KS) & 1][0];                     \
        _Pragma("unroll") for (int nj = 0; nj < 4; ++nj)                      \
            bf[nj] = *(const half8*)(bb_ + bOffB[nj]);                        \
        _Pragma("unroll") for (int mi = 0; mi < 4; ++mi)                      \
            af[mi] = *(const half8*)((char*)Als + aOffB[mi]);                 \
        LGKM0;                                                                \
        __builtin_amdgcn_s_setprio(1);                                        \
        _Pragma("unroll") for (int mi = 0; mi < 4; ++mi)                      \
            _Pragma("unroll") for (int nj = 0; nj < 4; ++nj)                  \
                acc[mi][nj] = __builtin_amdgcn_mfma_f32_16x16x32_f16(         \
                    af[mi], bf[nj], acc[mi][nj], 0, 0, 0);                    \
        __builtin_amdgcn_s_setprio(0);                                        \
    }

    // ---- prologue: A(0) then B(0) issued; in-flight = {A0 x4, B0 x2} ----
    LOADA(0);
    STAGE_B(0);

    // ---- main loop: ks = 0..30 ----
    // bar1 | WAITV(2): retire A(ks) (1 iter old) | cvt+write A(ks) |
    // issue A(ks+1), stage B(ks+1) | WAITV(6): retire B(ks) (1 iter old) |
    // lgkm0 | bar2 | 16 MFMA on (A(ks), B(ks)).
    for (int ks = 0; ks < 31; ++ks) {
        LGKM0;
        BAR;
        WAITV(2);                 // FIFO [A(ks)4, B(ks)2] -> retire A(ks)
        CVTA();
        LOADA(ks + 1);            // +4
        STAGE_B(ks + 1);          // +2 -> [B(ks)2, A(+1)4, B(+1)2]
        WAITV(6);                 // retire B(ks); 6 stay in flight
        LGKM0;                    // A ds_writes visible
        BAR;
        COMPUTE(ks);
    }
    // ---- tail: ks = 31 ----
    LGKM0;
    BAR;
    WAITV(2);                     // retire A(31)
    CVTA();
    WAITV(0);                     // retire B(31)
    LGKM0;
    BAR;
    COMPUTE(31);

#undef STAGE_B
#undef LOADA
#undef CVTA
#undef COMPUTE

    // ---- epilogue: e = acc + hb -> tanh -> * v -> per-row partial ----
    float vv[4];
#pragma unroll
    for (int nj = 0; nj < 4; ++nj)
        vv[nj] = vvec[ncol0 + wn * 64 + nj * 16 + l15];
#pragma unroll
    for (int mi = 0; mi < 4; ++mi) {
#pragma unroll
        for (int rg = 0; rg < 4; ++rg) {
            int rl = wm * 64 + mi * 16 + l4 * 4 + rg;     // local row 0..127
            const float* hbrow = hb + (size_t)((mrow0 + rl) & 31) * 1024
                                 + ncol0 + wn * 64 + l15;
            float sum = 0.f;
#pragma unroll
            for (int nj = 0; nj < 4; ++nj) {
                float e  = acc[mi][nj][rg] + hbrow[nj * 16];
                float e2 = __expf(2.f * e);
                sum += (1.f - 2.f / (e2 + 1.f)) * vv[nj];  // tanh(e) * v
            }
            float p = sum;
            p += __shfl_xor(p, 1);
            p += __shfl_xor(p, 2);
            p += __shfl_xor(p, 4);
            p += __shfl_xor(p, 8);
            if (l15 == 0) red[wn][rl] = p;
        }
    }
    __syncthreads();
    if (tid < 128) {
        float s = red[0][tid] + red[1][tid];
        partout[(size_t)nq * MROWS + mrow0 + tid] = s;
    }
}

// ---------------------------------------------------------------------------
// softmax over S=2048 per batch row; sums the 8 N-slice partials first.
// ---------------------------------------------------------------------------
__global__ __launch_bounds__(256) void softmax_rows(const float* __restrict__ part,
                                                    float* __restrict__ out) {
    const int b = blockIdx.x;
    const int tid  = threadIdx.x;
    const int lane = tid & 63;
    const int wv   = tid >> 6;
    __shared__ float sred[4];
    __shared__ float ssum[4];
    float x[8];
    float mx = -3.4e38f;
#pragma unroll
    for (int j = 0; j < 8; ++j) {
        int flat = (tid + j * 256) * 32 + b;              // row = s*32 + b
        float v = 0.f;
#pragma unroll
        for (int q = 0; q < 8; ++q) v += part[(size_t)q * MROWS + flat];
        x[j] = v;
        mx = fmaxf(mx, v);
    }
#pragma unroll
    for (int o = 1; o < 64; o <<= 1) mx = fmaxf(mx, __shfl_xor(mx, o));
    if (lane == 0) sred[wv] = mx;
    __syncthreads();
    mx = fmaxf(fmaxf(sred[0], sred[1]), fmaxf(sred[2], sred[3]));
    float s = 0.f;
#pragma unroll
    for (int j = 0; j < 8; ++j) { x[j] = __expf(x[j] - mx); s += x[j]; }
#pragma unroll
    for (int o = 1; o < 64; o <<= 1) s += __shfl_xor(s, o);
    if (lane == 0) ssum[wv] = s;
    __syncthreads();
    s = ssum[0] + ssum[1] + ssum[2] + ssum[3];
    float inv = 1.f / s;
#pragma unroll
    for (int j = 0; j < 8; ++j) out[(size_t)b * SEQ + tid + j * 256] = x[j] * inv;
}

extern "C" void kernel_launch(void* const* d_in, const int* in_sizes, int n_in,
                              void* d_out, int out_size, void* d_ws, size_t ws_size,
                              hipStream_t stream) {
    const float* hidden = (const float*)d_in[0];   // [32][1024]
    const float* enc    = (const float*)d_in[1];   // [2048][32][1024]
    const float* attn_w = (const float*)d_in[2];   // [2048][1024]
    const float* attn_b = (const float*)d_in[3];   // [1024]
    const float* v      = (const float*)d_in[4];   // [1024]
    float* out = (float*)d_out;                    // [32][2048]

    f16*   wt   = (f16*)d_ws;                              // 2 MB tiled We
    float* hb   = (float*)((char*)d_ws + 2097152);         // 128 KB
    float* part = (float*)((char*)d_ws + 2097152 + 131072); // 2 MB (8 slices)

    prep_w<<<512, 256, 0, stream>>>(attn_w, wt);
    prep_hb<<<128, 256, 0, stream>>>(hidden, attn_w, attn_b, hb);
    fused_energy<<<4096, 256, 0, stream>>>(enc, wt, hb, v, part);
    softmax_rows<<<32, 256, 0, stream>>>(part, out);
}

// Round 15
// 290.404 us; speedup vs baseline: 1.3908x; 1.0175x over previous
//
#include <hip/hip_runtime.h>

// Bahdanau attention fused kernel for MI355X (gfx950).
// scores[b][s] = softmax_s( v . tanh( hb[b,:] + enc[s,b,:] @ We ) )
// R13: R12 + COALESCED A staging. Old LOADA was 64-scattered-lines/instr
//      (TA-bound, the invariant bottleneck across R2..R12). New: flat-chunk
//      mapping, 128B segments, ds_write_b64 to linear Als, trivial frag reads.

typedef _Float16 f16;
typedef _Float16 half4 __attribute__((ext_vector_type(4)));
typedef _Float16 half8 __attribute__((ext_vector_type(8)));
typedef float f32x4 __attribute__((ext_vector_type(4)));

#define KDIM 1024
#define SEQ  2048
#define MROWS 65536

typedef __attribute__((address_space(1))) void gvoid;
typedef __attribute__((address_space(3))) void svoid;

__device__ __forceinline__ void gload_lds16(const void* g, void* l) {
    __builtin_amdgcn_global_load_lds((const gvoid*)g, (svoid*)l, 16, 0, 0);
}

// ---------------------------------------------------------------------------
// prep_w: transpose + f16-convert enc-half of attn_w into [128 n][32 k] tile
// images. Tile tk = nq*32 + ks (nq 0..7, ks 0..31), 8KB each; 16B block
// p = nloc*4 + ((kblk + (nloc>>1)) & 3); payload k = 1024+ks*32+kblk*8+j.
// ---------------------------------------------------------------------------
__global__ __launch_bounds__(256) void prep_w(const float* __restrict__ w,
                                              f16* __restrict__ wt) {
    int idx  = blockIdx.x * 256 + threadIdx.x;   // 0..131071
    int kblk = idx & 3;
    int nloc = (idx >> 2) & 127;
    int tk   = idx >> 9;                         // 0..255
    int ks   = tk & 31, nq = tk >> 5;
    int n_g  = nq * 128 + nloc;
    int kb   = 1024 + ks * 32 + kblk * 8;
    half8 h;
#pragma unroll
    for (int j = 0; j < 8; ++j)
        h[j] = (f16)w[(size_t)(kb + j) * 1024 + n_g];
    int p = nloc * 4 + ((kblk + (nloc >> 1)) & 3);
    *(half8*)&wt[(size_t)tk * 4096 + p * 8] = h;
}

// ---------------------------------------------------------------------------
// prep_hb: hb[b][n] = attn_b[n] + sum_k hidden[b][k] * attn_w[k][n]  (f32)
// ---------------------------------------------------------------------------
__global__ __launch_bounds__(256) void prep_hb(const float* __restrict__ hidden,
                                               const float* __restrict__ attn_w,
                                               const float* __restrict__ attn_b,
                                               float* __restrict__ hb) {
    int b = blockIdx.x >> 2;
    int n = (blockIdx.x & 3) * 256 + threadIdx.x;
    const float* h = hidden + (size_t)b * 1024;
    float acc = attn_b[n];
#pragma unroll 8
    for (int k = 0; k < 1024; ++k)
        acc += h[k] * attn_w[(size_t)k * 1024 + n];
    hb[(size_t)b * 1024 + n] = acc;
}

// ---------------------------------------------------------------------------
// fused_energy: block = 128 rows x 128 N-slice (nq of 8); K = 32 steps of 32.
// 4 waves (2M x 2N), wave tile 64x64, frags 4(M) x 4(N), 16 MFMA/step/wave.
// A staging COALESCED: round i, thread t -> chunk c=i*256+t -> (row=c>>3,
// k16=c&7); 8 lanes/row read 128B contiguous. Als linear [128 row][8 granule].
// ---------------------------------------------------------------------------
__global__ __launch_bounds__(256, 3)
void fused_energy(const float* __restrict__ enc, const f16* __restrict__ wt,
                  const float* __restrict__ hb, const float* __restrict__ vvec,
                  float* __restrict__ partout) {
    __shared__ f16 Bls[2][4096];   // 2 x 8KB B double buffer
    __shared__ f16 Als[4096];      // 8KB A tile, linear [row][k16 granule]
    __shared__ float red[2][128];

    const int tid  = threadIdx.x;
    const int lane = tid & 63;
    const int wv   = tid >> 6;          // 0..3
    const int wm   = wv >> 1;           // 0..1: 64-row group
    const int wn   = wv & 1;            // 0..1: 64-col group
    const int l15  = lane & 15;
    const int l4   = lane >> 4;

    // XCD mapping: all 8 nq-slices of a row-tile consecutive on one XCD
    const int bid   = blockIdx.x;       // 0..4095
    const int xcd   = bid & 7;
    const int chunk = bid >> 3;         // 0..511
    const int mt    = xcd * 64 + (chunk >> 3);   // 0..511
    const int nq    = chunk & 7;                 // 0..7
    const int mrow0 = mt * 128;
    const int ncol0 = nq * 128;

    const char* wtNq = (const char*)wt + (size_t)nq * 32 * 8192;

    // A staging (coalesced): thread t, round i: chunk c = i*256+t,
    // row = i*32 + (t>>3), k16 = t&7. Global: 8 lanes/row -> 128B segment.
    const int arow0 = tid >> 3;         // 0..31 (round adds i*32)
    const int ak16  = tid & 7;          // 16B granule within row
    const float* aG = enc + (size_t)(mrow0 + arow0) * KDIM + ak16 * 4;
    char* const aW  = (char*)Als + arow0 * 64 + ak16 * 8;   // + i*2048

    int aOffB[4], bOffB[4];
#pragma unroll
    for (int mi = 0; mi < 4; ++mi) {
        int r = wm * 64 + mi * 16 + l15;
        aOffB[mi] = r * 64 + l4 * 16;   // linear Als fragment read
    }
#pragma unroll
    for (int nj = 0; nj < 4; ++nj) {
        int n = wn * 64 + nj * 16 + l15;
        bOffB[nj] = (n * 4 + ((l4 + (n >> 1)) & 3)) * 16;
    }

    const f32x4 zero = {0.f, 0.f, 0.f, 0.f};
    f32x4 acc[4][4];
#pragma unroll
    for (int mi = 0; mi < 4; ++mi)
#pragma unroll
        for (int nj = 0; nj < 4; ++nj) acc[mi][nj] = zero;

    f32x4 rA[4];
    half8 bf[4], af[4];

#define WAITV(N) asm volatile("s_waitcnt vmcnt(" #N ")" ::: "memory")
#define LGKM0    asm volatile("s_waitcnt lgkmcnt(0)" ::: "memory")
#define BAR      __builtin_amdgcn_s_barrier()

#define STAGE_B(KS)                                                           \
    {                                                                         \
        const char* s_ = wtNq + (size_t)(KS) * 8192 + tid * 16;               \
        char* d_ = (char*)&Bls[(KS) & 1][0] + tid * 16;                       \
        gload_lds16(s_, d_);                                                  \
        gload_lds16(s_ + 4096, d_ + 4096);                                    \
    }
// 4 coalesced loads: round i reads rows i*32+(t>>3), 128B segment per 8 lanes
#define LOADA(KS)                                                             \
    {                                                                         \
        const float* p_ = aG + (KS) * 32;                                     \
        rA[0] = *(const f32x4*)(p_);                                          \
        rA[1] = *(const f32x4*)(p_ + 32 * KDIM);                              \
        rA[2] = *(const f32x4*)(p_ + 64 * KDIM);                              \
        rA[3] = *(const f32x4*)(p_ + 96 * KDIM);                              \
    }
#define CVTA()                                                                \
    {                                                                         \
        _Pragma("unroll") for (int i = 0; i < 4; ++i) {                       \
            half4 h_;                                                         \
            _Pragma("unroll") for (int j = 0; j < 4; ++j)                     \
                h_[j] = (f16)rA[i][j];                                        \
            *(half4*)(aW + i * 2048) = h_;                                    \
        }                                                                     \
    }
#define COMPUTE(KS)                                                           \
    {                                                                         \
        const char* bb_ = (const char*)&Bls[(KS) & 1][0];                     \
        _Pragma("unroll") for (int nj = 0; nj < 4; ++nj)                      \
            bf[nj] = *(const half8*)(bb_ + bOffB[nj]);                        \
        _Pragma("unroll") for (int mi = 0; mi < 4; ++mi)                      \
            af[mi] = *(const half8*)((char*)Als + aOffB[mi]);                 \
        LGKM0;                                                                \
        __builtin_amdgcn_s_setprio(1);                                        \
        _Pragma("unroll") for (int mi = 0; mi < 4; ++mi)                      \
            _Pragma("unroll") for (int nj = 0; nj < 4; ++nj)                  \
                acc[mi][nj] = __builtin_amdgcn_mfma_f32_16x16x32_f16(         \
                    af[mi], bf[nj], acc[mi][nj], 0, 0, 0);                    \
        __builtin_amdgcn_s_setprio(0);                                        \
    }

    // ---- prologue: A(0) then B(0) issued; in-flight = {A0 x4, B0 x2} ----
    LOADA(0);
    STAGE_B(0);

    // ---- main loop: ks = 0..30 ----
    // bar1 | WAITV(2): retire A(ks) (1 iter old) | cvt+write A(ks) |
    // issue A(ks+1), stage B(ks+1) | WAITV(6): retire B(ks) (1 iter old) |
    // lgkm0 | bar2 | 16 MFMA on (A(ks), B(ks)).
    for (int ks = 0; ks < 31; ++ks) {
        LGKM0;
        BAR;
        WAITV(2);                 // FIFO [A(ks)4, B(ks)2] -> retire A(ks)
        CVTA();
        LOADA(ks + 1);            // +4
        STAGE_B(ks + 1);          // +2 -> [B(ks)2, A(+1)4, B(+1)2]
        WAITV(6);                 // retire B(ks); 6 stay in flight
        LGKM0;                    // A ds_writes visible
        BAR;
        COMPUTE(ks);
    }
    // ---- tail: ks = 31 ----
    LGKM0;
    BAR;
    WAITV(2);                     // retire A(31)
    CVTA();
    WAITV(0);                     // retire B(31)
    LGKM0;
    BAR;
    COMPUTE(31);

#undef STAGE_B
#undef LOADA
#undef CVTA
#undef COMPUTE

    // ---- epilogue: e = acc + hb -> tanh -> * v -> per-row partial ----
    float vv[4];
#pragma unroll
    for (int nj = 0; nj < 4; ++nj)
        vv[nj] = vvec[ncol0 + wn * 64 + nj * 16 + l15];
#pragma unroll
    for (int mi = 0; mi < 4; ++mi) {
#pragma unroll
        for (int rg = 0; rg < 4; ++rg) {
            int rl = wm * 64 + mi * 16 + l4 * 4 + rg;     // local row 0..127
            const float* hbrow = hb + (size_t)((mrow0 + rl) & 31) * 1024
                                 + ncol0 + wn * 64 + l15;
            float sum = 0.f;
#pragma unroll
            for (int nj = 0; nj < 4; ++nj) {
                float e  = acc[mi][nj][rg] + hbrow[nj * 16];
                float e2 = __expf(2.f * e);
                sum += (1.f - 2.f / (e2 + 1.f)) * vv[nj];  // tanh(e) * v
            }
            float p = sum;
            p += __shfl_xor(p, 1);
            p += __shfl_xor(p, 2);
            p += __shfl_xor(p, 4);
            p += __shfl_xor(p, 8);
            if (l15 == 0) red[wn][rl] = p;
        }
    }
    __syncthreads();
    if (tid < 128) {
        float s = red[0][tid] + red[1][tid];
        partout[(size_t)nq * MROWS + mrow0 + tid] = s;
    }
}

// ---------------------------------------------------------------------------
// softmax over S=2048 per batch row; sums the 8 N-slice partials first.
// ---------------------------------------------------------------------------
__global__ __launch_bounds__(256) void softmax_rows(const float* __restrict__ part,
                                                    float* __restrict__ out) {
    const int b = blockIdx.x;
    const int tid  = threadIdx.x;
    const int lane = tid & 63;
    const int wv   = tid >> 6;
    __shared__ float sred[4];
    __shared__ float ssum[4];
    float x[8];
    float mx = -3.4e38f;
#pragma unroll
    for (int j = 0; j < 8; ++j) {
        int flat = (tid + j * 256) * 32 + b;              // row = s*32 + b
        float v = 0.f;
#pragma unroll
        for (int q = 0; q < 8; ++q) v += part[(size_t)q * MROWS + flat];
        x[j] = v;
        mx = fmaxf(mx, v);
    }
#pragma unroll
    for (int o = 1; o < 64; o <<= 1) mx = fmaxf(mx, __shfl_xor(mx, o));
    if (lane == 0) sred[wv] = mx;
    __syncthreads();
    mx = fmaxf(fmaxf(sred[0], sred[1]), fmaxf(sred[2], sred[3]));
    float s = 0.f;
#pragma unroll
    for (int j = 0; j < 8; ++j) { x[j] = __expf(x[j] - mx); s += x[j]; }
#pragma unroll
    for (int o = 1; o < 64; o <<= 1) s += __shfl_xor(s, o);
    if (lane == 0) ssum[wv] = s;
    __syncthreads();
    s = ssum[0] + ssum[1] + ssum[2] + ssum[3];
    float inv = 1.f / s;
#pragma unroll
    for (int j = 0; j < 8; ++j) out[(size_t)b * SEQ + tid + j * 256] = x[j] * inv;
}

extern "C" void kernel_launch(void* const* d_in, const int* in_sizes, int n_in,
                              void* d_out, int out_size, void* d_ws, size_t ws_size,
                              hipStream_t stream) {
    const float* hidden = (const float*)d_in[0];   // [32][1024]
    const float* enc    = (const float*)d_in[1];   // [2048][32][1024]
    const float* attn_w = (const float*)d_in[2];   // [2048][1024]
    const float* attn_b = (const float*)d_in[3];   // [1024]
    const float* v      = (const float*)d_in[4];   // [1024]
    float* out = (float*)d_out;                    // [32][2048]

    f16*   wt   = (f16*)d_ws;                              // 2 MB tiled We
    float* hb   = (float*)((char*)d_ws + 2097152);         // 128 KB
    float* part = (float*)((char*)d_ws + 2097152 + 131072); // 2 MB (8 slices)

    prep_w<<<512, 256, 0, stream>>>(attn_w, wt);
    prep_hb<<<128, 256, 0, stream>>>(hidden, attn_w, attn_b, hb);
    fused_energy<<<4096, 256, 0, stream>>>(enc, wt, hb, v, part);
    softmax_rows<<<32, 256, 0, stream>>>(part, out);
}